// Round 3
// baseline (118.390 us; speedup 1.0000x reference)
//
#include <hip/hip_runtime.h>

// IntegerNeuron: spiking-neuron scan over T with soft reset.
// x_accum [T,B,C,H,W] f32; per-channel scale/bias/vth [C]; tau scalar; is_first_layer int.
// out = spikes [T,B,C,H,W] f32 (0.0 or 1.0).
//
// Pure streaming op (zero reuse): 256 MiB read + 256 MiB write.
// R1: float4 + reg-carried mem -> 118us (4.5 TB/s).
// R2: non-temporal loads/stores -> 100us (5.4 TB/s).
// R3: 4 planes per 1024-thread block (16KB contiguous per t-slab per block,
//     was 4KB) to improve DRAM row-buffer locality across the 16 concurrent
//     address streams (8 read slabs + 8 write slabs, 128MB apart).
//
// Bit-exactness vs numpy f32 reference is mandatory (binary output):
//  - rintf (half-to-even) to match np.round
//  - explicit __fmul_rn/__fadd_rn so no FMA contraction changes mem rounding
//  - op order matches reference exactly: ((mem + x*tau) + bias_scaled)

#define T_STEPS 8
#define C_CH    256
#define HW      1024
#define EPS_F   1e-12f
#define PLANES_PER_BLOCK 4   // 1024 threads, 256 per plane

typedef float v4f __attribute__((ext_vector_type(4)));

__global__ __launch_bounds__(1024) void integer_neuron_kernel(
    const float* __restrict__ x,          // [T, B*C*HW]
    const float* __restrict__ prev_scale, // [C]
    const float* __restrict__ prev_bias,  // [C]
    const float* __restrict__ vth,        // [C]
    const float* __restrict__ tau_p,      // [1]
    const int*   __restrict__ is_first_p, // [1]
    float* __restrict__ out,              // [T, B*C*HW]
    long long n_planes)                   // B*C
{
    const float tau      = tau_p[0];
    const int   is_first = is_first_p[0];
    // drive = x_accum if is_first else x_accum * tau. Multiplying by exactly
    // 1.0f is bit-identical to the identity for finite inputs.
    const float drive_mul = is_first ? 1.0f : tau;

    // Block covers 4 consecutive planes; each thread owns one float4 within
    // its plane. Channel index is wave-uniform (256 threads = 4 waves/plane).
    const long long plane = (long long)blockIdx.x * PLANES_PER_BLOCK
                          + (threadIdx.x >> 8);          // tid/256
    const int c = (int)(plane % C_CH);

    // Per-channel constants; exact reference op order:
    //   round(b*tau/(s+EPS)), round(v*tau/(s+EPS)) with round = half-to-even.
    const float denom       = __fadd_rn(prev_scale[c], EPS_F);
    const float bias_scaled = rintf(__fdiv_rn(__fmul_rn(prev_bias[c], tau), denom));
    const float vth_scaled  = rintf(__fdiv_rn(__fmul_rn(vth[c],       tau), denom));

    const long long N    = n_planes * (long long)HW;     // stride per time step
    const long long base = plane * (long long)HW
                         + (long long)(threadIdx.x & 255) * 4;

    float mx = 0.0f, my = 0.0f, mz = 0.0f, mw = 0.0f;

    #pragma unroll
    for (int t = 0; t < T_STEPS; ++t) {
        const long long off = (long long)t * N + base;
        const v4f xv = __builtin_nontemporal_load(
            reinterpret_cast<const v4f*>(x + off));

        v4f sp;

        // component 0
        mx    = __fadd_rn(__fadd_rn(mx, __fmul_rn(xv.x, drive_mul)), bias_scaled);
        sp.x  = (mx >= vth_scaled) ? 1.0f : 0.0f;
        mx    = __fsub_rn(mx, __fmul_rn(sp.x, vth_scaled));
        // component 1
        my    = __fadd_rn(__fadd_rn(my, __fmul_rn(xv.y, drive_mul)), bias_scaled);
        sp.y  = (my >= vth_scaled) ? 1.0f : 0.0f;
        my    = __fsub_rn(my, __fmul_rn(sp.y, vth_scaled));
        // component 2
        mz    = __fadd_rn(__fadd_rn(mz, __fmul_rn(xv.z, drive_mul)), bias_scaled);
        sp.z  = (mz >= vth_scaled) ? 1.0f : 0.0f;
        mz    = __fsub_rn(mz, __fmul_rn(sp.z, vth_scaled));
        // component 3
        mw    = __fadd_rn(__fadd_rn(mw, __fmul_rn(xv.w, drive_mul)), bias_scaled);
        sp.w  = (mw >= vth_scaled) ? 1.0f : 0.0f;
        mw    = __fsub_rn(mw, __fmul_rn(sp.w, vth_scaled));

        __builtin_nontemporal_store(sp, reinterpret_cast<v4f*>(out + off));
    }
}

extern "C" void kernel_launch(void* const* d_in, const int* in_sizes, int n_in,
                              void* d_out, int out_size, void* d_ws, size_t ws_size,
                              hipStream_t stream) {
    const float* x          = (const float*)d_in[0]; // [T,B,C,H,W]
    const float* prev_scale = (const float*)d_in[1]; // [C]
    const float* prev_bias  = (const float*)d_in[2]; // [C]
    const float* vth        = (const float*)d_in[3]; // [C]
    const float* tau        = (const float*)d_in[4]; // [1]
    const int*   is_first   = (const int*)d_in[5];   // [1]
    float* out = (float*)d_out;

    // total elems = T * n_planes * HW; n_planes = B*C
    const long long total    = (long long)out_size;
    const long long n_planes = total / ((long long)T_STEPS * HW);

    dim3 grid((unsigned)(n_planes / PLANES_PER_BLOCK));  // 2048 blocks
    dim3 block(256 * PLANES_PER_BLOCK);                  // 1024 threads
    integer_neuron_kernel<<<grid, block, 0, stream>>>(
        x, prev_scale, prev_bias, vth, tau, is_first, out, n_planes);
}

// Round 4
// 95.124 us; speedup vs baseline: 1.2446x; 1.2446x over previous
//
#include <hip/hip_runtime.h>

// IntegerNeuron: spiking-neuron scan over T with soft reset.
// x_accum [T,B,C,H,W] f32; per-channel scale/bias/vth [C]; tau scalar; is_first_layer int.
// out = spikes [T,B,C,H,W] f32 (0.0 or 1.0).
//
// Pure streaming op (zero reuse): 256 MiB read + 256 MiB write.
// R1: float4 + reg-carried mem -> 118us (4.5 TB/s).
// R2: non-temporal loads/stores -> 100us (5.4 TB/s).
// R3: 4 planes per 1024-thread block -> 118us REGRESSED (big workgroups hurt;
//     footprint theory refuted). Reverted.
// R4: 2 float4 positions per thread (256-thread block covers 2 planes) to
//     double independent loads in flight: Little's law says 8 loads/thread
//     covers only ~470cy of ~900cy HBM latency -> latency-bound, not BW-bound.
//
// Bit-exactness vs numpy f32 reference is mandatory (binary output):
//  - rintf (half-to-even) to match np.round
//  - explicit __fmul_rn/__fadd_rn so no FMA contraction changes mem rounding
//  - op order matches reference exactly: ((mem + x*tau) + bias_scaled)

#define T_STEPS 8
#define C_CH    256
#define HW      1024
#define EPS_F   1e-12f

typedef float v4f __attribute__((ext_vector_type(4)));

// One soft-reset step on a float4 lane-group; ops bit-exact vs numpy.
#define STEP4(MEM0, MEM1, MEM2, MEM3, XV, SP)                                   \
    do {                                                                         \
        MEM0 = __fadd_rn(__fadd_rn(MEM0, __fmul_rn((XV).x, drive_mul)), bias_scaled); \
        (SP).x = (MEM0 >= vth_scaled) ? 1.0f : 0.0f;                             \
        MEM0 = __fsub_rn(MEM0, __fmul_rn((SP).x, vth_scaled));                   \
        MEM1 = __fadd_rn(__fadd_rn(MEM1, __fmul_rn((XV).y, drive_mul)), bias_scaled); \
        (SP).y = (MEM1 >= vth_scaled) ? 1.0f : 0.0f;                             \
        MEM1 = __fsub_rn(MEM1, __fmul_rn((SP).y, vth_scaled));                   \
        MEM2 = __fadd_rn(__fadd_rn(MEM2, __fmul_rn((XV).z, drive_mul)), bias_scaled); \
        (SP).z = (MEM2 >= vth_scaled) ? 1.0f : 0.0f;                             \
        MEM2 = __fsub_rn(MEM2, __fmul_rn((SP).z, vth_scaled));                   \
        MEM3 = __fadd_rn(__fadd_rn(MEM3, __fmul_rn((XV).w, drive_mul)), bias_scaled); \
        (SP).w = (MEM3 >= vth_scaled) ? 1.0f : 0.0f;                             \
        MEM3 = __fsub_rn(MEM3, __fmul_rn((SP).w, vth_scaled));                   \
    } while (0)

__global__ __launch_bounds__(256) void integer_neuron_kernel(
    const float* __restrict__ x,          // [T, B*C*HW]
    const float* __restrict__ prev_scale, // [C]
    const float* __restrict__ prev_bias,  // [C]
    const float* __restrict__ vth,        // [C]
    const float* __restrict__ tau_p,      // [1]
    const int*   __restrict__ is_first_p, // [1]
    float* __restrict__ out,              // [T, B*C*HW]
    long long n_planes)                   // B*C
{
    const float tau      = tau_p[0];
    const int   is_first = is_first_p[0];
    // drive = x_accum if is_first else x_accum * tau. Multiplying by exactly
    // 1.0f is bit-identical to the identity for finite inputs.
    const float drive_mul = is_first ? 1.0f : tau;

    // Block covers 2 planes: threads 0-127 -> plane A, 128-255 -> plane B.
    // Each thread owns two float4 positions 512 floats (2KB) apart within
    // its plane. Channel index is wave-uniform (waves sit inside one plane).
    const long long plane = (long long)blockIdx.x * 2 + (threadIdx.x >> 7);
    const int c = (int)(plane % C_CH);

    // Per-channel constants; exact reference op order:
    //   round(b*tau/(s+EPS)), round(v*tau/(s+EPS)) with round = half-to-even.
    const float denom       = __fadd_rn(prev_scale[c], EPS_F);
    const float bias_scaled = rintf(__fdiv_rn(__fmul_rn(prev_bias[c], tau), denom));
    const float vth_scaled  = rintf(__fdiv_rn(__fmul_rn(vth[c],       tau), denom));

    const long long N    = n_planes * (long long)HW;     // stride per time step
    const long long base = plane * (long long)HW
                         + (long long)(threadIdx.x & 127) * 4;

    float a0 = 0.0f, a1 = 0.0f, a2 = 0.0f, a3 = 0.0f;    // mem, position 0
    float b0 = 0.0f, b1 = 0.0f, b2 = 0.0f, b3 = 0.0f;    // mem, position 1

    #pragma unroll
    for (int t = 0; t < T_STEPS; ++t) {
        const long long off = (long long)t * N + base;
        const v4f xv0 = __builtin_nontemporal_load(
            reinterpret_cast<const v4f*>(x + off));
        const v4f xv1 = __builtin_nontemporal_load(
            reinterpret_cast<const v4f*>(x + off + 512));

        v4f sp0, sp1;
        STEP4(a0, a1, a2, a3, xv0, sp0);
        STEP4(b0, b1, b2, b3, xv1, sp1);

        __builtin_nontemporal_store(sp0, reinterpret_cast<v4f*>(out + off));
        __builtin_nontemporal_store(sp1, reinterpret_cast<v4f*>(out + off + 512));
    }
}

extern "C" void kernel_launch(void* const* d_in, const int* in_sizes, int n_in,
                              void* d_out, int out_size, void* d_ws, size_t ws_size,
                              hipStream_t stream) {
    const float* x          = (const float*)d_in[0]; // [T,B,C,H,W]
    const float* prev_scale = (const float*)d_in[1]; // [C]
    const float* prev_bias  = (const float*)d_in[2]; // [C]
    const float* vth        = (const float*)d_in[3]; // [C]
    const float* tau        = (const float*)d_in[4]; // [1]
    const int*   is_first   = (const int*)d_in[5];   // [1]
    float* out = (float*)d_out;

    // total elems = T * n_planes * HW; n_planes = B*C
    const long long total    = (long long)out_size;
    const long long n_planes = total / ((long long)T_STEPS * HW);

    dim3 grid((unsigned)(n_planes / 2));  // 4096 blocks, 2 planes each
    dim3 block(256);
    integer_neuron_kernel<<<grid, block, 0, stream>>>(
        x, prev_scale, prev_bias, vth, tau, is_first, out, n_planes);
}

// Round 5
// 89.494 us; speedup vs baseline: 1.3229x; 1.0629x over previous
//
#include <hip/hip_runtime.h>

// IntegerNeuron: spiking-neuron scan over T with soft reset.
// x_accum [T,B,C,H,W] f32; per-channel scale/bias/vth [C]; tau scalar; is_first_layer int.
// out = spikes [T,B,C,H,W] f32 (0.0 or 1.0).
//
// Pure streaming op (zero reuse): 256 MiB read + 256 MiB write.
// R1: float4 + reg-carried mem -> 118us (4.5 TB/s).
// R2: non-temporal loads/stores -> 100us (5.4 TB/s).
// R3: 1024-thread blocks -> 118us REGRESSED. Reverted.
// R4: 2 float4/thread (16 indep loads) -> 95us (5.65 TB/s). Latency-bound
//     theory confirmed; ILP is the lever.
// R5: 4 float4/thread (32 indep loads): each wave owns a full plane
//     (64 lanes x 4 pos x 4 floats = 1024 = HW). Grid 8192 -> 2048.
//
// Bit-exactness vs numpy f32 reference is mandatory (binary output):
//  - rintf (half-to-even) to match np.round
//  - explicit __fmul_rn/__fadd_rn so no FMA contraction changes mem rounding
//  - op order matches reference exactly: ((mem + x*tau) + bias_scaled)

#define T_STEPS 8
#define C_CH    256
#define HW      1024
#define EPS_F   1e-12f
#define NPOS    4    // float4 positions per thread

typedef float v4f __attribute__((ext_vector_type(4)));

__global__ __launch_bounds__(256) void integer_neuron_kernel(
    const float* __restrict__ x,          // [T, B*C*HW]
    const float* __restrict__ prev_scale, // [C]
    const float* __restrict__ prev_bias,  // [C]
    const float* __restrict__ vth,        // [C]
    const float* __restrict__ tau_p,      // [1]
    const int*   __restrict__ is_first_p, // [1]
    float* __restrict__ out,              // [T, B*C*HW]
    long long n_planes)                   // B*C
{
    const float tau      = tau_p[0];
    const int   is_first = is_first_p[0];
    // drive = x_accum if is_first else x_accum * tau. Multiplying by exactly
    // 1.0f is bit-identical to the identity for finite inputs.
    const float drive_mul = is_first ? 1.0f : tau;

    // Each wave (64 lanes) owns one full HW plane: lane l covers float4
    // positions l, l+64, l+128, l+192. Block = 4 waves = 4 planes.
    const long long plane = (long long)blockIdx.x * 4 + (threadIdx.x >> 6);
    const int c = (int)(plane % C_CH);

    // Per-channel constants; exact reference op order:
    //   round(b*tau/(s+EPS)), round(v*tau/(s+EPS)) with round = half-to-even.
    const float denom       = __fadd_rn(prev_scale[c], EPS_F);
    const float bias_scaled = rintf(__fdiv_rn(__fmul_rn(prev_bias[c], tau), denom));
    const float vth_scaled  = rintf(__fdiv_rn(__fmul_rn(vth[c],       tau), denom));

    const long long N    = n_planes * (long long)HW;     // stride per time step
    const long long base = plane * (long long)HW
                         + (long long)(threadIdx.x & 63) * 4;

    float mem[NPOS][4];
    #pragma unroll
    for (int p = 0; p < NPOS; ++p)
        #pragma unroll
        for (int j = 0; j < 4; ++j)
            mem[p][j] = 0.0f;

    #pragma unroll
    for (int t = 0; t < T_STEPS; ++t) {
        const long long off = (long long)t * N + base;

        v4f xv[NPOS];
        #pragma unroll
        for (int p = 0; p < NPOS; ++p)
            xv[p] = __builtin_nontemporal_load(
                reinterpret_cast<const v4f*>(x + off + p * 256));

        v4f sp[NPOS];
        #pragma unroll
        for (int p = 0; p < NPOS; ++p) {
            #pragma unroll
            for (int j = 0; j < 4; ++j) {
                float m = mem[p][j];
                m = __fadd_rn(__fadd_rn(m, __fmul_rn(xv[p][j], drive_mul)), bias_scaled);
                const float s = (m >= vth_scaled) ? 1.0f : 0.0f;
                mem[p][j] = __fsub_rn(m, __fmul_rn(s, vth_scaled));
                sp[p][j] = s;
            }
        }

        #pragma unroll
        for (int p = 0; p < NPOS; ++p)
            __builtin_nontemporal_store(sp[p],
                reinterpret_cast<v4f*>(out + off + p * 256));
    }
}

extern "C" void kernel_launch(void* const* d_in, const int* in_sizes, int n_in,
                              void* d_out, int out_size, void* d_ws, size_t ws_size,
                              hipStream_t stream) {
    const float* x          = (const float*)d_in[0]; // [T,B,C,H,W]
    const float* prev_scale = (const float*)d_in[1]; // [C]
    const float* prev_bias  = (const float*)d_in[2]; // [C]
    const float* vth        = (const float*)d_in[3]; // [C]
    const float* tau        = (const float*)d_in[4]; // [1]
    const int*   is_first   = (const int*)d_in[5];   // [1]
    float* out = (float*)d_out;

    // total elems = T * n_planes * HW; n_planes = B*C
    const long long total    = (long long)out_size;
    const long long n_planes = total / ((long long)T_STEPS * HW);

    dim3 grid((unsigned)(n_planes / 4));  // 2048 blocks, 4 planes each
    dim3 block(256);
    integer_neuron_kernel<<<grid, block, 0, stream>>>(
        x, prev_scale, prev_bias, vth, tau, is_first, out, n_planes);
}